// Round 6
// baseline (577.092 us; speedup 1.0000x reference)
//
#include <hip/hip_runtime.h>
#include <float.h>
#include <math.h>

#define THREADS 256
#define CAP 1536

typedef float f32x4 __attribute__((ext_vector_type(4)));
typedef unsigned short u16;
typedef u16 u16x8 __attribute__((ext_vector_type(8)));

// (v, idx) comparator implementing lax.top_k order: larger value wins,
// ties broken by LOWER index.
__device__ __forceinline__ bool better(float av, int ai, float bv, int bi) {
    return av > bv || (av == bv && ai < bi);
}

// ---------------------------------------------------------------------------
// Deterministic block reductions (256 threads = 4 waves of 64).
// ---------------------------------------------------------------------------
__device__ __forceinline__ void block_argmax(float& v, int& idx, float* wv, int* wi, int tid) {
    #pragma unroll
    for (int m = 32; m >= 1; m >>= 1) {
        float ov = __shfl_xor(v, m, 64);
        int   oi = __shfl_xor(idx, m, 64);
        if (better(ov, oi, v, idx)) { v = ov; idx = oi; }
    }
    if ((tid & 63) == 0) { wv[tid >> 6] = v; wi[tid >> 6] = idx; }
    __syncthreads();
    if (tid == 0) {
        float bv = wv[0]; int bi = wi[0];
        #pragma unroll
        for (int w = 1; w < 4; ++w) {
            if (better(wv[w], wi[w], bv, bi)) { bv = wv[w]; bi = wi[w]; }
        }
        wv[0] = bv; wi[0] = bi;
    }
    __syncthreads();
    v = wv[0]; idx = wi[0];
    __syncthreads();
}

__device__ __forceinline__ float block_sum(float v, float* wv, int tid) {
    #pragma unroll
    for (int m = 32; m >= 1; m >>= 1) v += __shfl_xor(v, m, 64);
    if ((tid & 63) == 0) wv[tid >> 6] = v;
    __syncthreads();
    if (tid == 0) wv[0] = wv[0] + wv[1] + wv[2] + wv[3];
    __syncthreads();
    float r = wv[0];
    __syncthreads();
    return r;
}

// Exact block top-8 merge: new t8 = top-8 of (old t8 ∪ cb[0..cc)).
// Deterministic: extraction is order-invariant on (value, index).
__device__ void compact_top8(float* cbv, int* cbi, int cc,
                             float* t8v, int* t8i,
                             float* wv, int* wi, int* ccnt, int tid) {
    float tv[8]; int ti[8];
    #pragma unroll
    for (int p = 0; p < 8; ++p) { tv[p] = -FLT_MAX; ti[p] = 0x7fffffff; }
    for (int k = tid; k < 8 + cc; k += THREADS) {     // virtual [t8 | cbuf]
        float v; int ix;
        if (k < 8) { v = t8v[k]; ix = t8i[k]; } else { v = cbv[k - 8]; ix = cbi[k - 8]; }
        if (better(v, ix, tv[7], ti[7])) {
            tv[7] = v; ti[7] = ix;
            #pragma unroll
            for (int p = 7; p > 0; --p) {
                if (better(tv[p], ti[p], tv[p - 1], ti[p - 1])) {
                    float tf = tv[p]; tv[p] = tv[p - 1]; tv[p - 1] = tf;
                    int   tt = ti[p]; ti[p] = ti[p - 1]; ti[p - 1] = tt;
                }
            }
        }
    }
    __syncthreads();                                   // t8 fully consumed
    for (int r = 0; r < 8; ++r) {
        float v = tv[0]; int ix = ti[0];
        block_argmax(v, ix, wv, wi, tid);
        if (ti[0] == ix) {                             // unique owner pops head
            #pragma unroll
            for (int p = 0; p < 7; ++p) { tv[p] = tv[p + 1]; ti[p] = ti[p + 1]; }
            tv[7] = -FLT_MAX; ti[7] = 0x7fffffff;
        }
        if (tid == 0) { t8v[r] = v; t8i[r] = ix; }
    }
    if (tid == 0) *ccnt = 0;
    __syncthreads();
}

// ---------------------------------------------------------------------------
// Kernel A: W[HH][S] fp32 -> Wtb[S][HH] bf16 (RNE).
// ---------------------------------------------------------------------------
__global__ __launch_bounds__(256) void transposeW_bf16(const float* __restrict__ W,
                                                       u16* __restrict__ Wtb,
                                                       int S, int HH) {
    __shared__ float tile[32][33];
    int x  = blockIdx.x * 32 + threadIdx.x;
    int y0 = blockIdx.y * 32;
    #pragma unroll
    for (int i = threadIdx.y; i < 32; i += 8) {
        int h = y0 + i;
        if (x < S && h < HH) tile[i][threadIdx.x] = W[(size_t)h * S + x];
    }
    __syncthreads();
    #pragma unroll
    for (int i = threadIdx.y; i < 32; i += 8) {
        int s = blockIdx.x * 32 + i;
        int h = y0 + threadIdx.x;
        if (s < S && h < HH) {
            unsigned u = __float_as_uint(tile[threadIdx.x][i]);
            unsigned r = (u + 0x7fffu + ((u >> 16) & 1u)) >> 16;   // RNE bf16
            Wtb[(size_t)s * HH + h] = (u16)r;
        }
    }
}

// ---------------------------------------------------------------------------
// Pure single-class stream kernels (diagnostic decomposition, R6).
// ---------------------------------------------------------------------------
__global__ __launch_bounds__(256) void copy_flat(const f32x4* __restrict__ in,
                                                 f32x4* __restrict__ out, long n4) {
    long i = (long)blockIdx.x * 256 + threadIdx.x;
    const long stride = (long)gridDim.x * 256;
    for (; i < n4; i += stride) out[i] = in[i];
}

__global__ __launch_bounds__(256) void fill_flat(f32x4* __restrict__ out, long n4, float val) {
    const f32x4 v = { val, val, val, val };
    long i = (long)blockIdx.x * 256 + threadIdx.x;
    const long stride = (long)gridDim.x * 256;
    for (; i < n4; i += stride) out[i] = v;
}

// ---------------------------------------------------------------------------
// Kernel D: per row — pure-read threshold scan for exact top-8, then the
// epilogue (gather, dedup, owner-compacted bf16 dots, softmax, scatter).
// Scan: seed threshold from first 1024 elements (one compaction), then a
// barrier-free append loop (expected ~230 appends/row); exact-fallback
// full re-scan if the LDS buffer ever overflows (provably order-safe).
// ---------------------------------------------------------------------------
__global__ __launch_bounds__(THREADS) void topk_senses(const float* __restrict__ hidden,
                                                       const float* __restrict__ pg,
                                                       const u16* __restrict__ Wtb,
                                                       const float* __restrict__ bias,
                                                       const int* __restrict__ graph,
                                                       float* __restrict__ outS,
                                                       int S, int V, int NBR) {
    __shared__ __align__(16) float sh_h[256];
    __shared__ float cbv[CAP];
    __shared__ int   cbi[CAP];
    __shared__ float t8v[8];
    __shared__ int   t8i[8];
    __shared__ int   cand[256];
    __shared__ float slog[256];
    __shared__ int   ol_s[256];
    __shared__ int   ol_t[256];
    __shared__ float wv[4];
    __shared__ int   wi[4];
    __shared__ int   ccnt, ocnt;

    const int row = blockIdx.x, tid = threadIdx.x;
    const int lane = tid & 63;

    sh_h[tid] = hidden[(size_t)row * 256 + tid];
    if (tid < 8) { t8v[tid] = -FLT_MAX; t8i[tid] = 0x7fffffff; }
    if (tid == 0) { ccnt = 0; ocnt = 0; }

    const f32x4* in4 = (const f32x4*)(pg + (size_t)row * V);
    const int nv4 = V >> 2;

    // seed: first 1024 elements verbatim into the candidate buffer
    {
        f32x4 val = in4[tid];
        #pragma unroll
        for (int c = 0; c < 4; ++c) { cbv[(tid << 2) | c] = val[c]; cbi[(tid << 2) | c] = (tid << 2) | c; }
    }
    __syncthreads();
    compact_top8(cbv, cbi, 4 * THREADS, t8v, t8i, wv, wi, &ccnt, tid);
    const float thr = t8v[7];

    // barrier-free scan of the rest (appends: v >= thr so value-ties can
    // compete by index; append order nondet but extraction order-invariant)
    for (int i = THREADS + tid; i < nv4; i += THREADS) {
        f32x4 val = in4[i];
        const int base = i << 2;
        #pragma unroll
        for (int c = 0; c < 4; ++c) {
            if (val[c] >= thr) {
                int pos = atomicAdd(&ccnt, 1);
                if (pos < CAP) { cbv[pos] = val[c]; cbi[pos] = base + c; }
            }
        }
    }
    for (int i2 = (nv4 << 2) + tid; i2 < V; i2 += THREADS) {   // scalar tail (none @30000)
        float v = pg[(size_t)row * V + i2];
        if (v >= thr) {
            int pos = atomicAdd(&ccnt, 1);
            if (pos < CAP) { cbv[pos] = v; cbi[pos] = i2; }
        }
    }
    __syncthreads();
    const int cc = ccnt;
    if (cc <= CAP) {
        compact_top8(cbv, cbi, cc, t8v, t8i, wv, wi, &ccnt, tid);
    } else {
        // overflow fallback (astronomically rare, kept for worst-case
        // exactness): full sorted-insert re-scan of the row.
        float tv[8]; int ti[8];
        #pragma unroll
        for (int p = 0; p < 8; ++p) { tv[p] = -FLT_MAX; ti[p] = 0x7fffffff; }
        for (int i = tid; i < nv4; i += THREADS) {
            f32x4 val = in4[i];
            const int base = i << 2;
            #pragma unroll
            for (int c = 0; c < 4; ++c) {
                if (better(val[c], base + c, tv[7], ti[7])) {
                    tv[7] = val[c]; ti[7] = base + c;
                    #pragma unroll
                    for (int p = 7; p > 0; --p) {
                        if (better(tv[p], ti[p], tv[p - 1], ti[p - 1])) {
                            float tf = tv[p]; tv[p] = tv[p - 1]; tv[p - 1] = tf;
                            int   tt = ti[p]; ti[p] = ti[p - 1]; ti[p - 1] = tt;
                        }
                    }
                }
            }
        }
        for (int i2 = (nv4 << 2) + tid; i2 < V; i2 += THREADS) {
            float v = pg[(size_t)row * V + i2];
            if (better(v, i2, tv[7], ti[7])) {
                tv[7] = v; ti[7] = i2;
                #pragma unroll
                for (int p = 7; p > 0; --p) {
                    if (better(tv[p], ti[p], tv[p - 1], ti[p - 1])) {
                        float tf = tv[p]; tv[p] = tv[p - 1]; tv[p - 1] = tf;
                        int   tt = ti[p]; ti[p] = ti[p - 1]; ti[p - 1] = tt;
                    }
                }
            }
        }
        __syncthreads();
        for (int r = 0; r < 8; ++r) {
            float v = tv[0]; int ix = ti[0];
            block_argmax(v, ix, wv, wi, tid);
            if (ti[0] == ix) {
                #pragma unroll
                for (int p = 0; p < 7; ++p) { tv[p] = tv[p + 1]; ti[p] = ti[p + 1]; }
                tv[7] = -FLT_MAX; ti[7] = 0x7fffffff;
            }
            if (tid == 0) { t8v[r] = v; t8i[r] = ix; }
        }
        __syncthreads();
    }

    // ---- gather candidate neighbours: 8 topk rows x 32 nbrs, coalesced
    const int j8 = tid >> 5, c32 = tid & 31;
    int my = -1;
    if (c32 < NBR) {
        int g = graph[(size_t)(t8i[j8] + S) * NBR + c32] - 1;
        my = (g >= 0 && g < S) ? g : -1;
    }
    cand[tid] = my;
    __syncthreads();

    // ---- dedup (owner = lowest slot with this sense) + owner compaction
    bool owner = (my >= 0);
    if (owner) {
        for (int t = 0; t < tid; ++t) {
            if (cand[t] == my) { owner = false; break; }
        }
    }
    if (owner) {
        int pos = atomicAdd(&ocnt, 1);          // order nondet; results keyed by slot
        ol_s[pos] = my; ol_t[pos] = tid;
    }
    __syncthreads();
    int nsel = ocnt;
    if (nsel == 0) {                            // zero-neighbour fallback: sense 0
        if (tid == 0) { ol_s[0] = 0; ol_t[0] = 0; owner = true; my = 0; }
        nsel = 1;
        __syncthreads();
    }
    const int nowners = nsel;

    // ---- owner-compacted bf16 dots: each wave loads 2 senses (1KB), each
    //      32-lane half reduces one sense; logit -> slog[original slot].
    {
        const int wid2 = (tid >> 6) << 1;       // {0,2,4,6}
        const int half = lane >> 5;             // 0 | 1
        const int l32  = lane & 31;
        const f32x4 hA = ((const f32x4*)sh_h)[l32 * 2];
        const f32x4 hB = ((const f32x4*)sh_h)[l32 * 2 + 1];
        for (int i = wid2; i < nowners; i += 8) {
            const int iB = (i + 1 < nowners) ? i + 1 : i;
            const int sense = half ? ol_s[iB] : ol_s[i];
            const u16x8 w8 = *(const u16x8*)(Wtb + (size_t)sense * 256 + l32 * 8);
            float acc = 0.f;
            #pragma unroll
            for (int c = 0; c < 8; ++c) {
                float wf = __uint_as_float(((unsigned)w8[c]) << 16);
                float hf = (c < 4) ? hA[c] : hB[c - 4];
                acc = fmaf(wf, hf, acc);
            }
            #pragma unroll
            for (int m = 16; m >= 1; m >>= 1) acc += __shfl_xor(acc, m, 64);
            if (l32 == 0) slog[half ? ol_t[iB] : ol_t[i]] = acc + bias[sense];
        }
    }
    __syncthreads();

    // ---- slot-ordered softmax (deterministic), delta at argmax, scatter
    const float logit = owner ? slog[tid] : -FLT_MAX;
    float mv = logit;
    int   ai = owner ? my : 0x7fffffff;
    block_argmax(mv, ai, wv, wi, tid);          // tie -> lowest sense (ref argmax)

    const float e = owner ? expf(logit - mv) : 0.f;
    const float sum = block_sum(e, wv, tid);
    if (owner) {
        float p = e / sum;
        if (my == ai) p -= 1e-8f * (float)(S - nsel);
        outS[(size_t)row * S + my] = logf(p);
    }
}

// ---------------------------------------------------------------------------
extern "C" void kernel_launch(void* const* d_in, const int* in_sizes, int n_in,
                              void* d_out, int out_size, void* d_ws, size_t ws_size,
                              hipStream_t stream) {
    const float* hidden = (const float*)d_in[0];
    const float* pg     = (const float*)d_in[1];
    const float* W      = (const float*)d_in[2];
    const float* bias   = (const float*)d_in[3];
    const int*   graph  = (const int*)d_in[4];
    // d_in[5] is K; fixed at 8 by the problem spec.

    const int S   = in_sizes[3];
    const int HH  = in_sizes[2] / S;   // 256
    const int N   = in_sizes[0] / HH;
    const int V   = in_sizes[1] / N;
    const int NBR = in_sizes[4] / (S + V);

    u16* Wtb = (u16*)d_ws;             // S*HH bf16

    float* outg = (float*)d_out;
    float* outS = outg + (size_t)N * V;

    const float LOGEPS = -18.420680743952367f;   // logf(1e-8f)

    dim3 tb(32, 8);
    dim3 tg((S + 31) / 32, (HH + 31) / 32);
    transposeW_bf16<<<tg, tb, 0, stream>>>(W, Wtb, S, HH);

    const long nCopy4 = ((long)N * V) >> 2;      // V*N % 4 == 0 here
    const long nFill4 = ((long)N * S) >> 2;
    copy_flat<<<8192, 256, 0, stream>>>((const f32x4*)pg, (f32x4*)outg, nCopy4);
    fill_flat<<<8192, 256, 0, stream>>>((f32x4*)outS, nFill4, LOGEPS);

    topk_senses<<<N, THREADS, 0, stream>>>(hidden, pg, Wtb, bias, graph, outS, S, V, NBR);
}

// Round 7
// 546.646 us; speedup vs baseline: 1.0557x; 1.0557x over previous
//
#include <hip/hip_runtime.h>
#include <float.h>
#include <math.h>
#include <string.h>

#define THREADS 256
#define CAP 1536

typedef float f32x4 __attribute__((ext_vector_type(4)));
typedef unsigned short u16;
typedef u16 u16x8 __attribute__((ext_vector_type(8)));

// (v, idx) comparator implementing lax.top_k order: larger value wins,
// ties broken by LOWER index.
__device__ __forceinline__ bool better(float av, int ai, float bv, int bi) {
    return av > bv || (av == bv && ai < bi);
}

// ---------------------------------------------------------------------------
// Deterministic block reductions (256 threads = 4 waves of 64).
// ---------------------------------------------------------------------------
__device__ __forceinline__ void block_argmax(float& v, int& idx, float* wv, int* wi, int tid) {
    #pragma unroll
    for (int m = 32; m >= 1; m >>= 1) {
        float ov = __shfl_xor(v, m, 64);
        int   oi = __shfl_xor(idx, m, 64);
        if (better(ov, oi, v, idx)) { v = ov; idx = oi; }
    }
    if ((tid & 63) == 0) { wv[tid >> 6] = v; wi[tid >> 6] = idx; }
    __syncthreads();
    if (tid == 0) {
        float bv = wv[0]; int bi = wi[0];
        #pragma unroll
        for (int w = 1; w < 4; ++w) {
            if (better(wv[w], wi[w], bv, bi)) { bv = wv[w]; bi = wi[w]; }
        }
        wv[0] = bv; wi[0] = bi;
    }
    __syncthreads();
    v = wv[0]; idx = wi[0];
    __syncthreads();
}

__device__ __forceinline__ float block_sum(float v, float* wv, int tid) {
    #pragma unroll
    for (int m = 32; m >= 1; m >>= 1) v += __shfl_xor(v, m, 64);
    if ((tid & 63) == 0) wv[tid >> 6] = v;
    __syncthreads();
    if (tid == 0) wv[0] = wv[0] + wv[1] + wv[2] + wv[3];
    __syncthreads();
    float r = wv[0];
    __syncthreads();
    return r;
}

// Exact block top-8 merge: new t8 = top-8 of (old t8 ∪ cb[0..cc)).
// Deterministic: extraction is order-invariant on (value, index).
__device__ void compact_top8(float* cbv, int* cbi, int cc,
                             float* t8v, int* t8i,
                             float* wv, int* wi, int* ccnt, int tid) {
    float tv[8]; int ti[8];
    #pragma unroll
    for (int p = 0; p < 8; ++p) { tv[p] = -FLT_MAX; ti[p] = 0x7fffffff; }
    for (int k = tid; k < 8 + cc; k += THREADS) {     // virtual [t8 | cbuf]
        float v; int ix;
        if (k < 8) { v = t8v[k]; ix = t8i[k]; } else { v = cbv[k - 8]; ix = cbi[k - 8]; }
        if (better(v, ix, tv[7], ti[7])) {
            tv[7] = v; ti[7] = ix;
            #pragma unroll
            for (int p = 7; p > 0; --p) {
                if (better(tv[p], ti[p], tv[p - 1], ti[p - 1])) {
                    float tf = tv[p]; tv[p] = tv[p - 1]; tv[p - 1] = tf;
                    int   tt = ti[p]; ti[p] = ti[p - 1]; ti[p - 1] = tt;
                }
            }
        }
    }
    __syncthreads();                                   // t8 fully consumed
    for (int r = 0; r < 8; ++r) {
        float v = tv[0]; int ix = ti[0];
        block_argmax(v, ix, wv, wi, tid);
        if (ti[0] == ix) {                             // unique owner pops head
            #pragma unroll
            for (int p = 0; p < 7; ++p) { tv[p] = tv[p + 1]; ti[p] = ti[p + 1]; }
            tv[7] = -FLT_MAX; ti[7] = 0x7fffffff;
        }
        if (tid == 0) { t8v[r] = v; t8i[r] = ix; }
    }
    if (tid == 0) *ccnt = 0;
    __syncthreads();
}

__device__ __forceinline__ void scan4(const f32x4& val, int base, float thr,
                                      float* cbv, int* cbi, int* ccnt) {
    #pragma unroll
    for (int c = 0; c < 4; ++c) {
        if (val[c] >= thr) {              // >=: value-ties must compete by index
            int pos = atomicAdd(ccnt, 1);
            if (pos < CAP) { cbv[pos] = val[c]; cbi[pos] = base + c; }
        }
    }
}

// ---------------------------------------------------------------------------
// Kernel A: W[HH][S] fp32 -> Wtb[S][HH] bf16 (RNE).
// ---------------------------------------------------------------------------
__global__ __launch_bounds__(256) void transposeW_bf16(const float* __restrict__ W,
                                                       u16* __restrict__ Wtb,
                                                       int S, int HH) {
    __shared__ float tile[32][33];
    int x  = blockIdx.x * 32 + threadIdx.x;
    int y0 = blockIdx.y * 32;
    #pragma unroll
    for (int i = threadIdx.y; i < 32; i += 8) {
        int h = y0 + i;
        if (x < S && h < HH) tile[i][threadIdx.x] = W[(size_t)h * S + x];
    }
    __syncthreads();
    #pragma unroll
    for (int i = threadIdx.y; i < 32; i += 8) {
        int s = blockIdx.x * 32 + i;
        int h = y0 + threadIdx.x;
        if (s < S && h < HH) {
            unsigned u = __float_as_uint(tile[threadIdx.x][i]);
            unsigned r = (u + 0x7fffu + ((u >> 16) & 1u)) >> 16;   // RNE bf16
            Wtb[(size_t)s * HH + h] = (u16)r;
        }
    }
}

// ---------------------------------------------------------------------------
// Kernel D: per row — pure-read threshold scan for exact top-8 (2-way
// unrolled loads for MLP), then the epilogue: gather, dedup, owner-compacted
// bf16 dots, slot-ordered softmax, delta at argmax, scatter into outS
// (which the preceding hipMemsetD32Async filled with log(EPS)).
// ---------------------------------------------------------------------------
__global__ __launch_bounds__(THREADS) void topk_senses(const float* __restrict__ hidden,
                                                       const float* __restrict__ pg,
                                                       const u16* __restrict__ Wtb,
                                                       const float* __restrict__ bias,
                                                       const int* __restrict__ graph,
                                                       float* __restrict__ outS,
                                                       int S, int V, int NBR) {
    __shared__ __align__(16) float sh_h[256];
    __shared__ float cbv[CAP];
    __shared__ int   cbi[CAP];
    __shared__ float t8v[8];
    __shared__ int   t8i[8];
    __shared__ int   cand[256];
    __shared__ float slog[256];
    __shared__ int   ol_s[256];
    __shared__ int   ol_t[256];
    __shared__ float wv[4];
    __shared__ int   wi[4];
    __shared__ int   ccnt, ocnt;

    const int row = blockIdx.x, tid = threadIdx.x;
    const int lane = tid & 63;

    sh_h[tid] = hidden[(size_t)row * 256 + tid];
    if (tid < 8) { t8v[tid] = -FLT_MAX; t8i[tid] = 0x7fffffff; }
    if (tid == 0) { ccnt = 0; ocnt = 0; }

    const f32x4* in4 = (const f32x4*)(pg + (size_t)row * V);
    const int nv4 = V >> 2;

    // seed: first 1024 elements verbatim into the candidate buffer
    {
        f32x4 val = in4[tid];
        #pragma unroll
        for (int c = 0; c < 4; ++c) { cbv[(tid << 2) | c] = val[c]; cbi[(tid << 2) | c] = (tid << 2) | c; }
    }
    __syncthreads();
    compact_top8(cbv, cbi, 4 * THREADS, t8v, t8i, wv, wi, &ccnt, tid);
    const float thr = t8v[7];

    // barrier-free threshold scan, 2 independent loads in flight per iter
    int i = THREADS + tid;
    for (; i + THREADS < nv4; i += 2 * THREADS) {
        f32x4 a = in4[i];
        f32x4 b = in4[i + THREADS];
        scan4(a, i << 2, thr, cbv, cbi, &ccnt);
        scan4(b, (i + THREADS) << 2, thr, cbv, cbi, &ccnt);
    }
    for (; i < nv4; i += THREADS) {
        f32x4 a = in4[i];
        scan4(a, i << 2, thr, cbv, cbi, &ccnt);
    }
    for (int i2 = (nv4 << 2) + tid; i2 < V; i2 += THREADS) {   // scalar tail (none @30000)
        float v = pg[(size_t)row * V + i2];
        if (v >= thr) {
            int pos = atomicAdd(&ccnt, 1);
            if (pos < CAP) { cbv[pos] = v; cbi[pos] = i2; }
        }
    }
    __syncthreads();
    const int cc = ccnt;
    if (cc <= CAP) {
        compact_top8(cbv, cbi, cc, t8v, t8i, wv, wi, &ccnt, tid);
    } else {
        // overflow fallback (astronomically rare): exact sorted-insert re-scan
        float tv[8]; int ti[8];
        #pragma unroll
        for (int p = 0; p < 8; ++p) { tv[p] = -FLT_MAX; ti[p] = 0x7fffffff; }
        for (int q = tid; q < nv4; q += THREADS) {
            f32x4 val = in4[q];
            const int base = q << 2;
            #pragma unroll
            for (int c = 0; c < 4; ++c) {
                if (better(val[c], base + c, tv[7], ti[7])) {
                    tv[7] = val[c]; ti[7] = base + c;
                    #pragma unroll
                    for (int p = 7; p > 0; --p) {
                        if (better(tv[p], ti[p], tv[p - 1], ti[p - 1])) {
                            float tf = tv[p]; tv[p] = tv[p - 1]; tv[p - 1] = tf;
                            int   tt = ti[p]; ti[p] = ti[p - 1]; ti[p - 1] = tt;
                        }
                    }
                }
            }
        }
        for (int i2 = (nv4 << 2) + tid; i2 < V; i2 += THREADS) {
            float v = pg[(size_t)row * V + i2];
            if (better(v, i2, tv[7], ti[7])) {
                tv[7] = v; ti[7] = i2;
                #pragma unroll
                for (int p = 7; p > 0; --p) {
                    if (better(tv[p], ti[p], tv[p - 1], ti[p - 1])) {
                        float tf = tv[p]; tv[p] = tv[p - 1]; tv[p - 1] = tf;
                        int   tt = ti[p]; ti[p] = ti[p - 1]; ti[p - 1] = tt;
                    }
                }
            }
        }
        __syncthreads();
        for (int r = 0; r < 8; ++r) {
            float v = tv[0]; int ix = ti[0];
            block_argmax(v, ix, wv, wi, tid);
            if (ti[0] == ix) {
                #pragma unroll
                for (int p = 0; p < 7; ++p) { tv[p] = tv[p + 1]; ti[p] = ti[p + 1]; }
                tv[7] = -FLT_MAX; ti[7] = 0x7fffffff;
            }
            if (tid == 0) { t8v[r] = v; t8i[r] = ix; }
        }
        __syncthreads();
    }

    // ---- gather candidate neighbours: 8 topk rows x 32 nbrs, coalesced
    const int j8 = tid >> 5, c32 = tid & 31;
    int my = -1;
    if (c32 < NBR) {
        int g = graph[(size_t)(t8i[j8] + S) * NBR + c32] - 1;
        my = (g >= 0 && g < S) ? g : -1;
    }
    cand[tid] = my;
    __syncthreads();

    // ---- dedup (owner = lowest slot with this sense) + owner compaction
    bool owner = (my >= 0);
    if (owner) {
        for (int t = 0; t < tid; ++t) {
            if (cand[t] == my) { owner = false; break; }
        }
    }
    if (owner) {
        int pos = atomicAdd(&ocnt, 1);          // order nondet; results keyed by slot
        ol_s[pos] = my; ol_t[pos] = tid;
    }
    __syncthreads();
    int nsel = ocnt;
    if (nsel == 0) {                            // zero-neighbour fallback: sense 0
        if (tid == 0) { ol_s[0] = 0; ol_t[0] = 0; owner = true; my = 0; }
        nsel = 1;
        __syncthreads();
    }
    const int nowners = nsel;

    // ---- owner-compacted bf16 dots: each wave loads 2 senses (1KB), each
    //      32-lane half reduces one sense; logit -> slog[original slot].
    {
        const int wid2 = (tid >> 6) << 1;       // {0,2,4,6}
        const int half = lane >> 5;             // 0 | 1
        const int l32  = lane & 31;
        const f32x4 hA = ((const f32x4*)sh_h)[l32 * 2];
        const f32x4 hB = ((const f32x4*)sh_h)[l32 * 2 + 1];
        for (int q = wid2; q < nowners; q += 8) {
            const int qB = (q + 1 < nowners) ? q + 1 : q;
            const int sense = half ? ol_s[qB] : ol_s[q];
            const u16x8 w8 = *(const u16x8*)(Wtb + (size_t)sense * 256 + l32 * 8);
            float acc = 0.f;
            #pragma unroll
            for (int c = 0; c < 8; ++c) {
                float wf = __uint_as_float(((unsigned)w8[c]) << 16);
                float hf = (c < 4) ? hA[c] : hB[c - 4];
                acc = fmaf(wf, hf, acc);
            }
            #pragma unroll
            for (int m = 16; m >= 1; m >>= 1) acc += __shfl_xor(acc, m, 64);
            if (l32 == 0) slog[half ? ol_t[qB] : ol_t[q]] = acc + bias[sense];
        }
    }
    __syncthreads();

    // ---- slot-ordered softmax (deterministic), delta at argmax, scatter
    const float logit = owner ? slog[tid] : -FLT_MAX;
    float mv = logit;
    int   ai = owner ? my : 0x7fffffff;
    block_argmax(mv, ai, wv, wi, tid);          // tie -> lowest sense (ref argmax)

    const float e = owner ? expf(logit - mv) : 0.f;
    const float sum = block_sum(e, wv, tid);
    if (owner) {
        float p = e / sum;
        if (my == ai) p -= 1e-8f * (float)(S - nsel);
        outS[(size_t)row * S + my] = logf(p);
    }
}

// ---------------------------------------------------------------------------
extern "C" void kernel_launch(void* const* d_in, const int* in_sizes, int n_in,
                              void* d_out, int out_size, void* d_ws, size_t ws_size,
                              hipStream_t stream) {
    const float* hidden = (const float*)d_in[0];
    const float* pg     = (const float*)d_in[1];
    const float* W      = (const float*)d_in[2];
    const float* bias   = (const float*)d_in[3];
    const int*   graph  = (const int*)d_in[4];
    // d_in[5] is K; fixed at 8 by the problem spec.

    const int S   = in_sizes[3];
    const int HH  = in_sizes[2] / S;   // 256
    const int N   = in_sizes[0] / HH;
    const int V   = in_sizes[1] / N;
    const int NBR = in_sizes[4] / (S + V);

    u16* Wtb = (u16*)d_ws;             // S*HH bf16

    float* outg = (float*)d_out;
    float* outS = outg + (size_t)N * V;

    // bit pattern of log(1e-8) as fp32, for the 32-bit memset fill
    float logeps = logf(1e-8f);
    int logeps_bits;
    memcpy(&logeps_bits, &logeps, sizeof(int));

    dim3 tb(32, 8);
    dim3 tg((S + 31) / 32, (HH + 31) / 32);
    transposeW_bf16<<<tg, tb, 0, stream>>>(W, Wtb, S, HH);

    // bulk streams via rocclr's tuned kernels (R6 showed ours cap at ~3.4 TB/s
    // while rocclr's fill hits 6.75 in the same session)
    hipMemcpyAsync(outg, pg, (size_t)N * V * sizeof(float),
                   hipMemcpyDeviceToDevice, stream);
    hipMemsetD32Async((hipDeviceptr_t)outS, logeps_bits, (size_t)N * S, stream);

    topk_senses<<<N, THREADS, 0, stream>>>(hidden, pg, Wtb, bias, graph, outS, S, V, NBR);
}